// Round 20
// baseline (1052.611 us; speedup 1.0000x reference)
//
#include <hip/hip_runtime.h>
#include <cstdint>

// GPT forward, MI355X. B=4 T=1024 C=768 NH=12 HD=64 L=4 V=512.
// d_out = logits fp32 [B*T*V] ++ attn fp32 [L,B,NH,T,T].
// R20 = R19 + s_setprio around attention MFMA clusters (T5, isolated).

#define B_ 4
#define T_ 1024
#define C_ 768
#define NH_ 12
#define HD_ 64
#define L_ 4
#define V_ 512
#define C4_ 3072

typedef unsigned short u16;
typedef float f32x4 __attribute__((ext_vector_type(4)));
typedef short s16x8 __attribute__((ext_vector_type(8)));
typedef u16 u16x4 __attribute__((ext_vector_type(4)));
typedef u16 u16x8 __attribute__((ext_vector_type(8)));

__device__ __forceinline__ u16 f2b(float f){
  union { float f; unsigned u; } v; v.f = f;
  unsigned u = v.u + 0x7fffu + ((v.u >> 16) & 1u);
  return (u16)(u >> 16);
}

__device__ __forceinline__ float b2f(u16 b){
  return __uint_as_float(((unsigned)b) << 16);
}

__device__ __forceinline__ unsigned cvtpk(float lo, float hi){
  unsigned r;
  asm("v_cvt_pk_bf16_f32 %0, %1, %2" : "=v"(r) : "v"(lo), "v"(hi));
  return r;
}

__device__ __forceinline__ f32x4 mfma16(s16x8 a, s16x8 b, f32x4 c){
  return __builtin_amdgcn_mfma_f32_16x16x32_bf16(a, b, c, 0, 0, 0);
}

__device__ __forceinline__ void gload16(const void* g, void* l){
  __builtin_amdgcn_global_load_lds((const __attribute__((address_space(1))) unsigned*)g,
                                   (__attribute__((address_space(3))) unsigned*)l, 16, 0, 0);
}

// ---------------- fused embedding + first LayerNorm (x bf16) ----------------
__global__ __launch_bounds__(256) void embed_ln_kernel(const int* __restrict__ idx,
    const float* __restrict__ tok, const float* __restrict__ pos, const float* __restrict__ typ,
    const float* __restrict__ g, const float* __restrict__ bta,
    u16* __restrict__ x, u16* __restrict__ out){
  int lane = threadIdx.x & 63;
  int w = threadIdx.x >> 6;
  int row = blockIdx.x*4 + w;
  int t = row & (T_-1);
  int tk = idx[row];
  const float* tr = tok + (size_t)tk*C_;
  const float* pr = pos + (size_t)t*C_;
  float4 v[3];
  float s = 0.f;
  #pragma unroll
  for (int j=0;j<3;j++){
    int c = j*256 + lane*4;
    float4 a = *(const float4*)(tr + c);
    float4 p = *(const float4*)(pr + c);
    float4 ty = *(const float4*)(typ + c);
    v[j] = (float4){a.x+p.x+ty.x, a.y+p.y+ty.y, a.z+p.z+ty.z, a.w+p.w+ty.w};
    s += v[j].x + v[j].y + v[j].z + v[j].w;
  }
  #pragma unroll
  for (int o=32;o>0;o>>=1) s += __shfl_xor(s, o, 64);
  float mean = s * (1.0f/C_);
  float var = 0.f;
  #pragma unroll
  for (int j=0;j<3;j++){
    float dx=v[j].x-mean, dy=v[j].y-mean, dz=v[j].z-mean, dw=v[j].w-mean;
    var += dx*dx+dy*dy+dz*dz+dw*dw;
  }
  #pragma unroll
  for (int o=32;o>0;o>>=1) var += __shfl_xor(var, o, 64);
  float rs = rsqrtf(var*(1.0f/C_) + 1e-5f);
  u16* xr = x + (size_t)row*C_;
  u16* orow = out + (size_t)row*C_;
  #pragma unroll
  for (int j=0;j<3;j++){
    int c = j*256 + lane*4;
    u16x4 xv = { f2b(v[j].x), f2b(v[j].y), f2b(v[j].z), f2b(v[j].w) };
    *(u16x4*)(xr + c) = xv;
    float4 gg = *(const float4*)(g + c);
    float4 bb = *(const float4*)(bta + c);
    u16x4 o = { f2b((v[j].x-mean)*rs*gg.x + bb.x), f2b((v[j].y-mean)*rs*gg.y + bb.y),
                f2b((v[j].z-mean)*rs*gg.z + bb.z), f2b((v[j].w-mean)*rs*gg.w + bb.w) };
    *(u16x4*)(orow + c) = o;
  }
}

// ---------------- LayerNorm bf16 -> bf16, vectorized ----------------
__global__ __launch_bounds__(256) void ln_kernel(const u16* __restrict__ x,
    const float* __restrict__ g, const float* __restrict__ bta, u16* __restrict__ out){
  int lane = threadIdx.x & 63;
  int row = blockIdx.x*4 + (threadIdx.x >> 6);
  const u16* xr = x + (size_t)row*C_;
  float v[12];
  float s = 0.f;
  #pragma unroll
  for (int j=0;j<3;j++){
    int c = j*256 + lane*4;
    u16x4 xv = *(const u16x4*)(xr + c);
    #pragma unroll
    for (int e=0;e<4;e++){ v[j*4+e] = b2f(xv[e]); s += v[j*4+e]; }
  }
  #pragma unroll
  for (int o=32;o>0;o>>=1) s += __shfl_xor(s, o, 64);
  float mean = s * (1.0f/C_);
  float var = 0.f;
  #pragma unroll
  for (int j=0;j<12;j++){ float d = v[j]-mean; var += d*d; }
  #pragma unroll
  for (int o=32;o>0;o>>=1) var += __shfl_xor(var, o, 64);
  float rs = rsqrtf(var*(1.0f/C_) + 1e-5f);
  u16* orow = out + (size_t)row*C_;
  #pragma unroll
  for (int j=0;j<3;j++){
    int c = j*256 + lane*4;
    float4 gg = *(const float4*)(g + c);
    float4 bb = *(const float4*)(bta + c);
    u16x4 o = { f2b((v[j*4+0]-mean)*rs*gg.x + bb.x), f2b((v[j*4+1]-mean)*rs*gg.y + bb.y),
                f2b((v[j*4+2]-mean)*rs*gg.z + bb.z), f2b((v[j*4+3]-mean)*rs*gg.w + bb.w) };
    *(u16x4*)(orow + c) = o;
  }
}

// ---------------- fused weight transpose + fp32->bf16 ----------------
struct ConvTable {
  const float* src[7];
  u16* dst[7];
  int K[7], N[7], nTN[7], perZ[7];
  unsigned long long outStride[7];
  int start[8];
};

__global__ __launch_bounds__(256) void convT_all(ConvTable tab){
  int bid = blockIdx.x;
  int d = 0;
  #pragma unroll
  for (int j=1;j<7;j++) if (bid >= tab.start[j]) d = j;
  const float* src = nullptr; u16* dst = nullptr;
  int K=0, N=0, nTN=0, perZ=0; size_t oS=0;
  #pragma unroll
  for (int j=0;j<7;j++) if (d==j){ src=tab.src[j]; dst=tab.dst[j]; K=tab.K[j]; N=tab.N[j];
                                   nTN=tab.nTN[j]; perZ=tab.perZ[j]; oS=(size_t)tab.outStride[j]; }
  int local = bid - tab.start[d];
  int z = local / perZ;
  int rem = local - z*perZ;
  int tk = rem / nTN;
  int tn = rem - tk*nTN;
  int k0 = tk*64, n0 = tn*64;
  size_t inBase = (size_t)z * K * N;
  size_t outBase = (size_t)z * oS;

  __shared__ u16 t[64][68];
  #pragma unroll
  for (int rep=0;rep<4;rep++){
    int id = threadIdx.x + rep*256;
    int kr = id >> 4;
    int nc = (id & 15)*4;
    float4 v = *(const float4*)(src + inBase + (size_t)(k0+kr)*N + n0+nc);
    t[nc+0][kr] = f2b(v.x);
    t[nc+1][kr] = f2b(v.y);
    t[nc+2][kr] = f2b(v.z);
    t[nc+3][kr] = f2b(v.w);
  }
  __syncthreads();
  #pragma unroll
  for (int rep=0;rep<4;rep++){
    int id = threadIdx.x + rep*256;
    int nr = id >> 4;
    int kc = (id & 15)*4;
    u16x4 o = {t[nr][kc], t[nr][kc+1], t[nr][kc+2], t[nr][kc+3]};
    *(u16x4*)(dst + outBase + (size_t)(n0+nr)*K + k0+kc) = o;
  }
}

// ---------------- GEMM: R8 two-barrier counted-vmcnt loop + XCD swizzle ----------------
// C[M,N] = A[M,K] @ Bt[N,K]^T + bias. BN=128. BM in {64,128}.
// MODE 0: bf16 out [M,N] (+GELU), coalesced via LDS restage
// MODE 3: bf16 residual += via fp32-LDS restage, coalesced u16x8 RMW
// MODE 4: fp32 out
// MODE 5: fused QKV: q,k -> [B,NH,T,HD]; v -> [B,NH,HD,T] via LDS transpose
template<int BM, int MODE, bool GELU>
__global__ __launch_bounds__(256) void gemm_kernel(
    const u16* __restrict__ A, const u16* __restrict__ Bt,
    const float* __restrict__ bias, const float* __restrict__ bias2, const float* __restrict__ bias3,
    u16* __restrict__ outb, u16* __restrict__ outk, u16* __restrict__ outv,
    float* __restrict__ outf, u16* __restrict__ outx, int N, int K)
{
  constexpr int MT = BM/32;
  constexpr int BUF = (BM+128)*64;
  __shared__ u16 smem[2*BUF];
  const int tid = threadIdx.x;
  const int lane = tid & 63;
  const int w = tid >> 6;
  const int wm = w >> 1, wn = w & 1;

  const int gx = gridDim.x;
  const int nwg = gx * gridDim.y;
  int flat = blockIdx.y*gx + blockIdx.x;
  int swzb = (flat & 7)*(nwg >> 3) + (flat >> 3);
  const int m0 = (swzb / gx) * BM;
  const int n0 = (swzb % gx) * 128;

  const int cl = lane & 15, gr = lane >> 4;
  const int rsub = lane >> 3;
  const int swl = ((lane & 7) ^ rsub) * 8;

  f32x4 acc[MT][4];
  #pragma unroll
  for (int a=0;a<MT;a++)
    #pragma unroll
    for (int b=0;b<4;b++) acc[a][b] = (f32x4){0.f,0.f,0.f,0.f};

  auto stage = [&](int kk, u16* buf){
    u16* la = buf;
    u16* lb = buf + BM*64;
    #pragma unroll
    for (int j=0;j<MT;j++){
      int rowb = w*(BM/4) + j*8;
      gload16(A + (size_t)(m0+rowb+rsub)*K + kk + swl, &la[rowb*64]);
    }
    #pragma unroll
    for (int j=0;j<4;j++){
      int rowb = w*32 + j*8;
      gload16(Bt + (size_t)(n0+rowb+rsub)*K + kk + swl, &lb[rowb*64]);
    }
  };

  const int nSteps = K >> 6;
  stage(0, smem);

  for (int t=0; t<nSteps; t++){
    u16* cur = smem + (t&1)*BUF;
    u16* nxt = smem + ((t+1)&1)*BUF;
    if (t+1 < nSteps){
      stage((t+1)<<6, nxt);
      if constexpr (BM==128) asm volatile("s_waitcnt vmcnt(8)" ::: "memory");
      else                   asm volatile("s_waitcnt vmcnt(6)" ::: "memory");
    } else {
      asm volatile("s_waitcnt vmcnt(0)" ::: "memory");
    }
    __builtin_amdgcn_sched_barrier(0);
    __builtin_amdgcn_s_barrier();

    u16* la = cur;
    u16* lb = cur + BM*64;
    #pragma unroll
    for (int cc=0;cc<2;cc++){
      int ko = cc*32 + gr*8;
      s16x8 af[MT], bf[4];
      #pragma unroll
      for (int mt=0;mt<MT;mt++){
        int row = wm*(BM/2) + mt*16 + cl;
        af[mt] = *(const s16x8*)&la[row*64 + (ko ^ ((row&7)*8))];
      }
      #pragma unroll
      for (int nt=0;nt<4;nt++){
        int row = wn*64 + nt*16 + cl;
        bf[nt] = *(const s16x8*)&lb[row*64 + (ko ^ ((row&7)*8))];
      }
      #pragma unroll
      for (int mt=0;mt<MT;mt++)
        #pragma unroll
        for (int nt=0;nt<4;nt++)
          acc[mt][nt] = mfma16(af[mt], bf[nt], acc[mt][nt]);
    }
    __builtin_amdgcn_sched_barrier(0);
    __builtin_amdgcn_s_barrier();
  }

  if (MODE == 5){
    const int which = n0 / C_;
    const float* bp = (which==0) ? bias : (which==1) ? bias2 : bias3;
    const int nb = n0 - which*C_;
    #pragma unroll
    for (int mt=0;mt<MT;mt++){
      #pragma unroll
      for (int nt=0;nt<4;nt++){
        #pragma unroll
        for (int i=0;i<4;i++){
          int tl = wm*(BM/2) + mt*16 + gr*4 + i;
          int dl = wn*64 + nt*16 + cl;
          smem[tl*128 + (dl ^ ((tl&7)*8))] = f2b(acc[mt][nt][i] + bp[nb + dl]);
        }
      }
    }
    __syncthreads();
    const int b = m0 >> 10, tg = m0 & (T_-1);
    if (which < 2){
      u16* outp = which ? outk : outb;
      constexpr int TPR = 256/BM;
      constexpr int CPT = 16/TPR;
      int r = tid / TPR;
      int sub = tid % TPR;
      #pragma unroll
      for (int j=0;j<CPT;j++){
        int ch = sub*CPT + j;
        int h = (nb >> 6) + (ch >> 3);
        int dd = (ch & 7)*8;
        u16x8 vv = *(const u16x8*)&smem[r*128 + ((ch ^ (r&7))*8)];
        *(u16x8*)&outp[(((size_t)b*NH_ + h)*T_ + tg + r)*HD_ + dd] = vv;
      }
    } else {
      constexpr int TCH = BM/16;
      int r = tid >> 1;
      int half = tid & 1;
      int dg = nb + r;
      int h = dg >> 6, dd = dg & (HD_-1);
      u16* orow = outv + (((size_t)b*NH_ + h)*HD_ + dd)*T_ + tg;
      #pragma unroll
      for (int j=0;j<TCH;j++){
        int t0 = half*(BM/2) + j*8;
        u16x8 vv;
        #pragma unroll
        for (int s2=0;s2<8;s2++){
          int t = t0 + s2;
          vv[s2] = smem[t*128 + (r ^ ((t&7)*8))];
        }
        *(u16x8*)&orow[t0] = vv;
      }
    }
  } else if (MODE == 0){
    #pragma unroll
    for (int mt=0;mt<MT;mt++){
      #pragma unroll
      for (int nt=0;nt<4;nt++){
        #pragma unroll
        for (int i=0;i<4;i++){
          int tl = wm*(BM/2) + mt*16 + gr*4 + i;
          int dl = wn*64 + nt*16 + cl;
          float val = acc[mt][nt][i] + bias[n0 + dl];
          if (GELU) val = 0.5f*val*(1.0f + erff(val*0.70710678118654752440f));
          smem[tl*128 + (dl ^ ((tl&7)*8))] = f2b(val);
        }
      }
    }
    __syncthreads();
    constexpr int TPR = 256/BM;
    constexpr int CPT = 16/TPR;
    int r = tid / TPR;
    int sub = tid % TPR;
    u16* orow = outb + (size_t)(m0 + r)*N + n0;
    #pragma unroll
    for (int j=0;j<CPT;j++){
      int ch = sub*CPT + j;
      u16x8 vv = *(const u16x8*)&smem[r*128 + ((ch ^ (r&7))*8)];
      *(u16x8*)&orow[ch*8] = vv;
    }
  } else if (MODE == 3){
    static_assert(BM == 64, "MODE 3 fp32 restage sized for BM=64");
    float* lds_f = (float*)smem;       // 64*132*4 = 33792 B <= 49152 B
    #pragma unroll
    for (int mt=0;mt<MT;mt++){
      #pragma unroll
      for (int nt=0;nt<4;nt++){
        #pragma unroll
        for (int i=0;i<4;i++){
          int tl = wm*(BM/2) + mt*16 + gr*4 + i;
          int dl = wn*64 + nt*16 + cl;
          float val = acc[mt][nt][i];
          if (bias) val += bias[n0 + dl];
          lds_f[tl*132 + dl] = val;
        }
      }
    }
    __syncthreads();
    constexpr int TPR = 256/BM;        // 4 threads per row
    constexpr int CPT = 16/TPR;        // 4 u16x8 chunks per thread
    int r = tid / TPR;
    int sub = tid % TPR;
    u16* xrow = outx + (size_t)(m0 + r)*N + n0;
    #pragma unroll
    for (int j=0;j<CPT;j++){
      int ch = sub*CPT + j;
      u16x8 xv = *(const u16x8*)&xrow[ch*8];
      const float* lf = &lds_f[r*132 + ch*8];
      u16x8 ov;
      #pragma unroll
      for (int e=0;e<8;e++) ov[e] = f2b(b2f(xv[e]) + lf[e]);
      *(u16x8*)&xrow[ch*8] = ov;
    }
  } else {
    #pragma unroll
    for (int mt=0;mt<MT;mt++){
      #pragma unroll
      for (int nt=0;nt<4;nt++){
        #pragma unroll
        for (int i=0;i<4;i++){
          int gm = m0 + wm*(BM/2) + mt*16 + gr*4 + i;
          int gn = n0 + wn*64 + nt*16 + cl;
          float val = acc[mt][nt][i];
          if (bias) val += bias[gn];
          outf[(size_t)gm*N + gn] = val;
        }
      }
    }
  }
}

// ---------------- attention: R11-frozen body + setprio on MFMA; heavy tiles first ----------------
__global__ __launch_bounds__(256,2) void attn_kernel(
    const u16* __restrict__ q, const u16* __restrict__ k, const u16* __restrict__ vt,
    float* __restrict__ att, u16* __restrict__ y, int layer)
{
  __shared__ u16 pl[4][16*64];
  const int lane = threadIdx.x & 63;
  const int w = threadIdx.x >> 6;
  const int qt = 15 - blockIdx.x;
  const int bh = blockIdx.y;
  const int bb = bh / NH_;
  const int hh = bh - bb*NH_;
  const int q0 = qt*64 + w*16;
  const u16* qbase = q + (size_t)bh*T_*HD_;
  const u16* kbase = k + (size_t)bh*T_*HD_;
  const u16* vbase = vt + (size_t)bh*HD_*T_;
  float* abase = att + ((size_t)layer*B_*NH_ + bh)*((size_t)T_*T_);
  u16* plw = &pl[w][0];

  const int cl = lane & 15, gr = lane >> 4;
  const int d0 = gr*8;
  const int swz = (cl & 7)*8;
  const int myq = q0 + cl;

  s16x8 qf0 = *(const s16x8*)(qbase + (size_t)(q0+cl)*HD_ + d0);
  s16x8 qf1 = *(const s16x8*)(qbase + (size_t)(q0+cl)*HD_ + 32 + d0);

  const float scale = 0.125f;
  const int nkt = qt + 1;

  unsigned pbuf[16][8];
  float slocal = 0.f;
  f32x4 yacc[4];
  #pragma unroll
  for (int n=0;n<4;n++) yacc[n] = (f32x4){0.f,0.f,0.f,0.f};

  #pragma unroll
  for (int kt=0; kt<16; kt++){
    if (kt < nkt){
      #pragma unroll
      for (int n=0;n<4;n++){
        int krow = kt*64 + n*16 + cl;
        s16x8 kf0 = *(const s16x8*)(kbase + (size_t)krow*HD_ + d0);
        s16x8 kf1 = *(const s16x8*)(kbase + (size_t)krow*HD_ + 32 + d0);
        f32x4 dacc = (f32x4){0.f,0.f,0.f,0.f};
        __builtin_amdgcn_s_setprio(1);
        dacc = mfma16(kf0, qf0, dacc);
        dacc = mfma16(kf1, qf1, dacc);
        __builtin_amdgcn_s_setprio(0);
        float p[4];
        #pragma unroll
        for (int i=0;i<4;i++){
          float sv = dacc[i]*scale;
          int kk = kt*64 + n*16 + gr*4 + i;
          if (kt == qt && kk > myq) sv = -1e30f;
          p[i] = __expf(sv);
        }
        slocal += (p[0]+p[1]) + (p[2]+p[3]);
        unsigned lo = cvtpk(p[0],p[1]), hi = cvtpk(p[2],p[3]);
        pbuf[kt][2*n]   = lo;
        pbuf[kt][2*n+1] = hi;
        int colb = (n*16 + gr*4) ^ swz;
        *(uint2*)&plw[cl*64 + colb] = make_uint2(lo, hi);
      }
      asm volatile("s_waitcnt lgkmcnt(0)" ::: "memory");
      __builtin_amdgcn_sched_barrier(0);
      __builtin_amdgcn_s_setprio(1);
      #pragma unroll
      for (int cc=0;cc<2;cc++){
        s16x8 pa = *(const s16x8*)&plw[cl*64 + ((cc*32 + d0) ^ swz)];
        #pragma unroll
        for (int n2=0;n2<4;n2++){
          s16x8 bv = *(const s16x8*)(vbase + (size_t)(n2*16+cl)*T_ + kt*64 + cc*32 + d0);
          yacc[n2] = mfma16(pa, bv, yacc[n2]);
        }
      }
      __builtin_amdgcn_s_setprio(0);
    }
  }

  slocal += __shfl_xor(slocal, 16, 64);
  slocal += __shfl_xor(slocal, 32, 64);
  float inv = 1.0f / slocal;

  float invy[4];
  #pragma unroll
  for (int i=0;i<4;i++) invy[i] = __shfl(inv, gr*4 + i, 64);

  #pragma unroll
  for (int n2=0;n2<4;n2++){
    #pragma unroll
    for (int i=0;i<4;i++){
      int r = q0 + gr*4 + i;
      y[((size_t)bb*T_ + r)*C_ + hh*HD_ + n2*16 + cl] = f2b(yacc[n2][i]*invy[i]);
    }
  }

  #pragma unroll
  for (int kt=0; kt<16; kt++){
    if (kt < nkt){
      #pragma unroll
      for (int n=0;n<4;n++){
        unsigned lo = pbuf[kt][2*n], hi = pbuf[kt][2*n+1];
        float p0 = __uint_as_float(lo << 16)          * inv;
        float p1 = __uint_as_float(lo & 0xffff0000u)  * inv;
        float p2 = __uint_as_float(hi << 16)          * inv;
        float p3 = __uint_as_float(hi & 0xffff0000u)  * inv;
        *(float4*)&abase[(size_t)myq*T_ + kt*64 + n*16 + gr*4] = make_float4(p0,p1,p2,p3);
      }
    }
  }

  int kend = nkt*64;
  if (kend < T_){
    int w4 = (T_ - kend) >> 2;
    for (int r = w; r < 64; r += 4){
      float* rp = abase + (size_t)(qt*64 + r)*T_ + kend;
      for (int c = lane; c < w4; c += 64){
        *(float4*)(rp + c*4) = make_float4(0.f,0.f,0.f,0.f);
      }
    }
  }
}

// ---------------- host ----------------
extern "C" void kernel_launch(void* const* d_in, const int* in_sizes, int n_in,
                              void* d_out, int out_size, void* d_ws, size_t ws_size,
                              hipStream_t stream)
{
  (void)in_sizes; (void)n_in; (void)out_size; (void)ws_size;
  const int*   idx  = (const int*)d_in[0];
  const float* tok  = (const float*)d_in[1];
  const float* typ  = (const float*)d_in[2];
  const float* pos  = (const float*)d_in[3];
  const float* ln1s = (const float*)d_in[4];
  const float* ln1b = (const float*)d_in[5];
  const float* ln2s = (const float*)d_in[6];
  const float* ln2b = (const float*)d_in[7];
  const float* wq   = (const float*)d_in[8];
  const float* bq   = (const float*)d_in[9];
  const float* wk   = (const float*)d_in[10];
  const float* bk   = (const float*)d_in[11];
  const float* wv   = (const float*)d_in[12];
  const float* bv   = (const float*)d_in[13];
  const float* wp   = (const float*)d_in[14];
  const float* bp   = (const float*)d_in[15];
  const float* w1   = (const float*)d_in[16];
  const float* b1   = (const float*)d_in[17];
  const float* w2   = (const float*)d_in[18];
  const float* b2   = (const float*)d_in[19];
  const float* lnfs = (const float*)d_in[20];
  const float* lnfb = (const float*)d_in[21];
  const float* hw   = (const float*)d_in[22];

  char* ws = (char*)d_ws;
  u16* x      = (u16*)(ws + 0);
  u16* hbf    = (u16*)(ws + 12582912);
  u16* qb     = (u16*)(ws + 18874368);
  u16* kb     = (u16*)(ws + 25165824);
  u16* vtb    = (u16*)(ws + 31457280);
  u16* yb     = (u16*)(ws + 37748736);
  u16* h2     = (u16*)(ws + 44040192);
  u16* wqkvT  = (u16*)(ws + 69206016);
  u16* wpT    = (u16*)(ws + 83361792);
  u16* w1T    = (u16*)(ws + 88080384);
  u16* w2T    = (u16*)(ws + 106954752);
  u16* hwT    = (u16*)(ws + 125829120);

  float* logits = (float*)d_out;
  float* att = logits + (size_t)B_*T_*V_;

  const size_t CC   = (size_t)C_*C_;
  const size_t CC4  = (size_t)C_*C4_;
  const size_t QKVL = (size_t)3*C_*C_;

  ConvTable tab;
  const float* srcs[7] = {wq, wk, wv, wp, w1, w2, hw};
  u16* dsts[7] = {wqkvT, wqkvT + CC, wqkvT + 2*CC, wpT, w1T, w2T, hwT};
  int Ks[7]   = {C_, C_, C_, C_, C_,  C4_, C_};
  int Ns[7]   = {C_, C_, C_, C_, C4_, C_,  V_};
  int nzs[7]  = {L_, L_, L_, L_, L_,  L_,  1};
  unsigned long long oss[7] = {QKVL, QKVL, QKVL, CC, CC4, CC4, CC};
  int acc = 0;
  for (int j=0;j<7;j++){
    tab.src[j]=srcs[j]; tab.dst[j]=dsts[j]; tab.K[j]=Ks[j]; tab.N[j]=Ns[j];
    tab.nTN[j]=Ns[j]/64; tab.perZ[j]=(Ks[j]/64)*(Ns[j]/64); tab.outStride[j]=oss[j];
    tab.start[j]=acc; acc += tab.perZ[j]*nzs[j];
  }
  tab.start[7]=acc;
  convT_all<<<acc, 256, 0, stream>>>(tab);

  embed_ln_kernel<<<1024, 256, 0, stream>>>(idx, tok, pos, typ + C_, ln1s, ln1b, x, hbf);

  for (int l=0; l<L_; l++){
    if (l > 0)
      ln_kernel<<<1024, 256, 0, stream>>>(x, ln1s + l*C_, ln1b + l*C_, hbf);
    gemm_kernel<64,5,false><<<dim3(18,64), 256, 0, stream>>>(
        hbf, wqkvT + l*QKVL, bq + l*C_, bk + l*C_, bv + l*C_,
        qb, kb, vtb, nullptr, nullptr, 3*C_, C_);
    attn_kernel<<<dim3(16,48), 256, 0, stream>>>(qb, kb, vtb, att, yb, l);
    gemm_kernel<64,3,false><<<dim3(6,64), 256, 0, stream>>>(
        yb, wpT + l*CC, bp + l*C_, nullptr, nullptr,
        nullptr, nullptr, nullptr, nullptr, x, C_, C_);
    ln_kernel<<<1024, 256, 0, stream>>>(x, ln2s + l*C_, ln2b + l*C_, hbf);
    gemm_kernel<64,0,true><<<dim3(24,64), 256, 0, stream>>>(
        hbf, w1T + l*CC4, b1 + l*C4_, nullptr, nullptr,
        h2, nullptr, nullptr, nullptr, nullptr, C4_, C_);
    gemm_kernel<64,3,false><<<dim3(6,64), 256, 0, stream>>>(
        h2, w2T + l*CC4, b2 + l*C_, nullptr, nullptr,
        nullptr, nullptr, nullptr, nullptr, x, C_, C4_);
  }
  ln_kernel<<<1024, 256, 0, stream>>>(x, lnfs, lnfb, hbf);
  gemm_kernel<64,4,false><<<dim3(4,64), 256, 0, stream>>>(
      hbf, hwT, nullptr, nullptr, nullptr,
      nullptr, nullptr, nullptr, logits, nullptr, V_, C_);
}

// Round 21
// 1039.649 us; speedup vs baseline: 1.0125x; 1.0125x over previous
//
#include <hip/hip_runtime.h>
#include <cstdint>

// GPT forward, MI355X. B=4 T=1024 C=768 NH=12 HD=64 L=4 V=512.
// d_out = logits fp32 [B*T*V] ++ attn fp32 [L,B,NH,T,T].
// R21 = R19 (best green, 1040us): bf16 residual, MODE-3 fp32-LDS restage RMW,
// separate vectorized LN, R8 GEMM loop + XCD swizzle, frozen attention.

#define B_ 4
#define T_ 1024
#define C_ 768
#define NH_ 12
#define HD_ 64
#define L_ 4
#define V_ 512
#define C4_ 3072

typedef unsigned short u16;
typedef float f32x4 __attribute__((ext_vector_type(4)));
typedef short s16x8 __attribute__((ext_vector_type(8)));
typedef u16 u16x4 __attribute__((ext_vector_type(4)));
typedef u16 u16x8 __attribute__((ext_vector_type(8)));

__device__ __forceinline__ u16 f2b(float f){
  union { float f; unsigned u; } v; v.f = f;
  unsigned u = v.u + 0x7fffu + ((v.u >> 16) & 1u);
  return (u16)(u >> 16);
}

__device__ __forceinline__ float b2f(u16 b){
  return __uint_as_float(((unsigned)b) << 16);
}

__device__ __forceinline__ unsigned cvtpk(float lo, float hi){
  unsigned r;
  asm("v_cvt_pk_bf16_f32 %0, %1, %2" : "=v"(r) : "v"(lo), "v"(hi));
  return r;
}

__device__ __forceinline__ f32x4 mfma16(s16x8 a, s16x8 b, f32x4 c){
  return __builtin_amdgcn_mfma_f32_16x16x32_bf16(a, b, c, 0, 0, 0);
}

__device__ __forceinline__ void gload16(const void* g, void* l){
  __builtin_amdgcn_global_load_lds((const __attribute__((address_space(1))) unsigned*)g,
                                   (__attribute__((address_space(3))) unsigned*)l, 16, 0, 0);
}

// ---------------- fused embedding + first LayerNorm (x bf16) ----------------
__global__ __launch_bounds__(256) void embed_ln_kernel(const int* __restrict__ idx,
    const float* __restrict__ tok, const float* __restrict__ pos, const float* __restrict__ typ,
    const float* __restrict__ g, const float* __restrict__ bta,
    u16* __restrict__ x, u16* __restrict__ out){
  int lane = threadIdx.x & 63;
  int w = threadIdx.x >> 6;
  int row = blockIdx.x*4 + w;
  int t = row & (T_-1);
  int tk = idx[row];
  const float* tr = tok + (size_t)tk*C_;
  const float* pr = pos + (size_t)t*C_;
  float4 v[3];
  float s = 0.f;
  #pragma unroll
  for (int j=0;j<3;j++){
    int c = j*256 + lane*4;
    float4 a = *(const float4*)(tr + c);
    float4 p = *(const float4*)(pr + c);
    float4 ty = *(const float4*)(typ + c);
    v[j] = (float4){a.x+p.x+ty.x, a.y+p.y+ty.y, a.z+p.z+ty.z, a.w+p.w+ty.w};
    s += v[j].x + v[j].y + v[j].z + v[j].w;
  }
  #pragma unroll
  for (int o=32;o>0;o>>=1) s += __shfl_xor(s, o, 64);
  float mean = s * (1.0f/C_);
  float var = 0.f;
  #pragma unroll
  for (int j=0;j<3;j++){
    float dx=v[j].x-mean, dy=v[j].y-mean, dz=v[j].z-mean, dw=v[j].w-mean;
    var += dx*dx+dy*dy+dz*dz+dw*dw;
  }
  #pragma unroll
  for (int o=32;o>0;o>>=1) var += __shfl_xor(var, o, 64);
  float rs = rsqrtf(var*(1.0f/C_) + 1e-5f);
  u16* xr = x + (size_t)row*C_;
  u16* orow = out + (size_t)row*C_;
  #pragma unroll
  for (int j=0;j<3;j++){
    int c = j*256 + lane*4;
    u16x4 xv = { f2b(v[j].x), f2b(v[j].y), f2b(v[j].z), f2b(v[j].w) };
    *(u16x4*)(xr + c) = xv;
    float4 gg = *(const float4*)(g + c);
    float4 bb = *(const float4*)(bta + c);
    u16x4 o = { f2b((v[j].x-mean)*rs*gg.x + bb.x), f2b((v[j].y-mean)*rs*gg.y + bb.y),
                f2b((v[j].z-mean)*rs*gg.z + bb.z), f2b((v[j].w-mean)*rs*gg.w + bb.w) };
    *(u16x4*)(orow + c) = o;
  }
}

// ---------------- LayerNorm bf16 -> bf16, vectorized ----------------
__global__ __launch_bounds__(256) void ln_kernel(const u16* __restrict__ x,
    const float* __restrict__ g, const float* __restrict__ bta, u16* __restrict__ out){
  int lane = threadIdx.x & 63;
  int row = blockIdx.x*4 + (threadIdx.x >> 6);
  const u16* xr = x + (size_t)row*C_;
  float v[12];
  float s = 0.f;
  #pragma unroll
  for (int j=0;j<3;j++){
    int c = j*256 + lane*4;
    u16x4 xv = *(const u16x4*)(xr + c);
    #pragma unroll
    for (int e=0;e<4;e++){ v[j*4+e] = b2f(xv[e]); s += v[j*4+e]; }
  }
  #pragma unroll
  for (int o=32;o>0;o>>=1) s += __shfl_xor(s, o, 64);
  float mean = s * (1.0f/C_);
  float var = 0.f;
  #pragma unroll
  for (int j=0;j<12;j++){ float d = v[j]-mean; var += d*d; }
  #pragma unroll
  for (int o=32;o>0;o>>=1) var += __shfl_xor(var, o, 64);
  float rs = rsqrtf(var*(1.0f/C_) + 1e-5f);
  u16* orow = out + (size_t)row*C_;
  #pragma unroll
  for (int j=0;j<3;j++){
    int c = j*256 + lane*4;
    float4 gg = *(const float4*)(g + c);
    float4 bb = *(const float4*)(bta + c);
    u16x4 o = { f2b((v[j*4+0]-mean)*rs*gg.x + bb.x), f2b((v[j*4+1]-mean)*rs*gg.y + bb.y),
                f2b((v[j*4+2]-mean)*rs*gg.z + bb.z), f2b((v[j*4+3]-mean)*rs*gg.w + bb.w) };
    *(u16x4*)(orow + c) = o;
  }
}

// ---------------- fused weight transpose + fp32->bf16 ----------------
struct ConvTable {
  const float* src[7];
  u16* dst[7];
  int K[7], N[7], nTN[7], perZ[7];
  unsigned long long outStride[7];
  int start[8];
};

__global__ __launch_bounds__(256) void convT_all(ConvTable tab){
  int bid = blockIdx.x;
  int d = 0;
  #pragma unroll
  for (int j=1;j<7;j++) if (bid >= tab.start[j]) d = j;
  const float* src = nullptr; u16* dst = nullptr;
  int K=0, N=0, nTN=0, perZ=0; size_t oS=0;
  #pragma unroll
  for (int j=0;j<7;j++) if (d==j){ src=tab.src[j]; dst=tab.dst[j]; K=tab.K[j]; N=tab.N[j];
                                   nTN=tab.nTN[j]; perZ=tab.perZ[j]; oS=(size_t)tab.outStride[j]; }
  int local = bid - tab.start[d];
  int z = local / perZ;
  int rem = local - z*perZ;
  int tk = rem / nTN;
  int tn = rem - tk*nTN;
  int k0 = tk*64, n0 = tn*64;
  size_t inBase = (size_t)z * K * N;
  size_t outBase = (size_t)z * oS;

  __shared__ u16 t[64][68];
  #pragma unroll
  for (int rep=0;rep<4;rep++){
    int id = threadIdx.x + rep*256;
    int kr = id >> 4;
    int nc = (id & 15)*4;
    float4 v = *(const float4*)(src + inBase + (size_t)(k0+kr)*N + n0+nc);
    t[nc+0][kr] = f2b(v.x);
    t[nc+1][kr] = f2b(v.y);
    t[nc+2][kr] = f2b(v.z);
    t[nc+3][kr] = f2b(v.w);
  }
  __syncthreads();
  #pragma unroll
  for (int rep=0;rep<4;rep++){
    int id = threadIdx.x + rep*256;
    int nr = id >> 4;
    int kc = (id & 15)*4;
    u16x4 o = {t[nr][kc], t[nr][kc+1], t[nr][kc+2], t[nr][kc+3]};
    *(u16x4*)(dst + outBase + (size_t)(n0+nr)*K + k0+kc) = o;
  }
}

// ---------------- GEMM: R8 two-barrier counted-vmcnt loop + XCD swizzle ----------------
// C[M,N] = A[M,K] @ Bt[N,K]^T + bias. BN=128. BM in {64,128}.
// MODE 0: bf16 out [M,N] (+GELU), coalesced via LDS restage
// MODE 3: bf16 residual += via fp32-LDS restage, coalesced u16x8 RMW
// MODE 4: fp32 out
// MODE 5: fused QKV: q,k -> [B,NH,T,HD]; v -> [B,NH,HD,T] via LDS transpose
template<int BM, int MODE, bool GELU>
__global__ __launch_bounds__(256) void gemm_kernel(
    const u16* __restrict__ A, const u16* __restrict__ Bt,
    const float* __restrict__ bias, const float* __restrict__ bias2, const float* __restrict__ bias3,
    u16* __restrict__ outb, u16* __restrict__ outk, u16* __restrict__ outv,
    float* __restrict__ outf, u16* __restrict__ outx, int N, int K)
{
  constexpr int MT = BM/32;
  constexpr int BUF = (BM+128)*64;
  __shared__ u16 smem[2*BUF];
  const int tid = threadIdx.x;
  const int lane = tid & 63;
  const int w = tid >> 6;
  const int wm = w >> 1, wn = w & 1;

  const int gx = gridDim.x;
  const int nwg = gx * gridDim.y;
  int flat = blockIdx.y*gx + blockIdx.x;
  int swzb = (flat & 7)*(nwg >> 3) + (flat >> 3);
  const int m0 = (swzb / gx) * BM;
  const int n0 = (swzb % gx) * 128;

  const int cl = lane & 15, gr = lane >> 4;
  const int rsub = lane >> 3;
  const int swl = ((lane & 7) ^ rsub) * 8;

  f32x4 acc[MT][4];
  #pragma unroll
  for (int a=0;a<MT;a++)
    #pragma unroll
    for (int b=0;b<4;b++) acc[a][b] = (f32x4){0.f,0.f,0.f,0.f};

  auto stage = [&](int kk, u16* buf){
    u16* la = buf;
    u16* lb = buf + BM*64;
    #pragma unroll
    for (int j=0;j<MT;j++){
      int rowb = w*(BM/4) + j*8;
      gload16(A + (size_t)(m0+rowb+rsub)*K + kk + swl, &la[rowb*64]);
    }
    #pragma unroll
    for (int j=0;j<4;j++){
      int rowb = w*32 + j*8;
      gload16(Bt + (size_t)(n0+rowb+rsub)*K + kk + swl, &lb[rowb*64]);
    }
  };

  const int nSteps = K >> 6;
  stage(0, smem);

  for (int t=0; t<nSteps; t++){
    u16* cur = smem + (t&1)*BUF;
    u16* nxt = smem + ((t+1)&1)*BUF;
    if (t+1 < nSteps){
      stage((t+1)<<6, nxt);
      if constexpr (BM==128) asm volatile("s_waitcnt vmcnt(8)" ::: "memory");
      else                   asm volatile("s_waitcnt vmcnt(6)" ::: "memory");
    } else {
      asm volatile("s_waitcnt vmcnt(0)" ::: "memory");
    }
    __builtin_amdgcn_sched_barrier(0);
    __builtin_amdgcn_s_barrier();

    u16* la = cur;
    u16* lb = cur + BM*64;
    #pragma unroll
    for (int cc=0;cc<2;cc++){
      int ko = cc*32 + gr*8;
      s16x8 af[MT], bf[4];
      #pragma unroll
      for (int mt=0;mt<MT;mt++){
        int row = wm*(BM/2) + mt*16 + cl;
        af[mt] = *(const s16x8*)&la[row*64 + (ko ^ ((row&7)*8))];
      }
      #pragma unroll
      for (int nt=0;nt<4;nt++){
        int row = wn*64 + nt*16 + cl;
        bf[nt] = *(const s16x8*)&lb[row*64 + (ko ^ ((row&7)*8))];
      }
      #pragma unroll
      for (int mt=0;mt<MT;mt++)
        #pragma unroll
        for (int nt=0;nt<4;nt++)
          acc[mt][nt] = mfma16(af[mt], bf[nt], acc[mt][nt]);
    }
    __builtin_amdgcn_sched_barrier(0);
    __builtin_amdgcn_s_barrier();
  }

  if (MODE == 5){
    const int which = n0 / C_;
    const float* bp = (which==0) ? bias : (which==1) ? bias2 : bias3;
    const int nb = n0 - which*C_;
    #pragma unroll
    for (int mt=0;mt<MT;mt++){
      #pragma unroll
      for (int nt=0;nt<4;nt++){
        #pragma unroll
        for (int i=0;i<4;i++){
          int tl = wm*(BM/2) + mt*16 + gr*4 + i;
          int dl = wn*64 + nt*16 + cl;
          smem[tl*128 + (dl ^ ((tl&7)*8))] = f2b(acc[mt][nt][i] + bp[nb + dl]);
        }
      }
    }
    __syncthreads();
    const int b = m0 >> 10, tg = m0 & (T_-1);
    if (which < 2){
      u16* outp = which ? outk : outb;
      constexpr int TPR = 256/BM;
      constexpr int CPT = 16/TPR;
      int r = tid / TPR;
      int sub = tid % TPR;
      #pragma unroll
      for (int j=0;j<CPT;j++){
        int ch = sub*CPT + j;
        int h = (nb >> 6) + (ch >> 3);
        int dd = (ch & 7)*8;
        u16x8 vv = *(const u16x8*)&smem[r*128 + ((ch ^ (r&7))*8)];
        *(u16x8*)&outp[(((size_t)b*NH_ + h)*T_ + tg + r)*HD_ + dd] = vv;
      }
    } else {
      constexpr int TCH = BM/16;
      int r = tid >> 1;
      int half = tid & 1;
      int dg = nb + r;
      int h = dg >> 6, dd = dg & (HD_-1);
      u16* orow = outv + (((size_t)b*NH_ + h)*HD_ + dd)*T_ + tg;
      #pragma unroll
      for (int j=0;j<TCH;j++){
        int t0 = half*(BM/2) + j*8;
        u16x8 vv;
        #pragma unroll
        for (int s2=0;s2<8;s2++){
          int t = t0 + s2;
          vv[s2] = smem[t*128 + (r ^ ((t&7)*8))];
        }
        *(u16x8*)&orow[t0] = vv;
      }
    }
  } else if (MODE == 0){
    #pragma unroll
    for (int mt=0;mt<MT;mt++){
      #pragma unroll
      for (int nt=0;nt<4;nt++){
        #pragma unroll
        for (int i=0;i<4;i++){
          int tl = wm*(BM/2) + mt*16 + gr*4 + i;
          int dl = wn*64 + nt*16 + cl;
          float val = acc[mt][nt][i] + bias[n0 + dl];
          if (GELU) val = 0.5f*val*(1.0f + erff(val*0.70710678118654752440f));
          smem[tl*128 + (dl ^ ((tl&7)*8))] = f2b(val);
        }
      }
    }
    __syncthreads();
    constexpr int TPR = 256/BM;
    constexpr int CPT = 16/TPR;
    int r = tid / TPR;
    int sub = tid % TPR;
    u16* orow = outb + (size_t)(m0 + r)*N + n0;
    #pragma unroll
    for (int j=0;j<CPT;j++){
      int ch = sub*CPT + j;
      u16x8 vv = *(const u16x8*)&smem[r*128 + ((ch ^ (r&7))*8)];
      *(u16x8*)&orow[ch*8] = vv;
    }
  } else if (MODE == 3){
    static_assert(BM == 64, "MODE 3 fp32 restage sized for BM=64");
    float* lds_f = (float*)smem;       // 64*132*4 = 33792 B <= 49152 B
    #pragma unroll
    for (int mt=0;mt<MT;mt++){
      #pragma unroll
      for (int nt=0;nt<4;nt++){
        #pragma unroll
        for (int i=0;i<4;i++){
          int tl = wm*(BM/2) + mt*16 + gr*4 + i;
          int dl = wn*64 + nt*16 + cl;
          float val = acc[mt][nt][i];
          if (bias) val += bias[n0 + dl];
          lds_f[tl*132 + dl] = val;
        }
      }
    }
    __syncthreads();
    constexpr int TPR = 256/BM;        // 4 threads per row
    constexpr int CPT = 16/TPR;        // 4 u16x8 chunks per thread
    int r = tid / TPR;
    int sub = tid % TPR;
    u16* xrow = outx + (size_t)(m0 + r)*N + n0;
    #pragma unroll
    for (int j=0;j<CPT;j++){
      int ch = sub*CPT + j;
      u16x8 xv = *(const u16x8*)&xrow[ch*8];
      const float* lf = &lds_f[r*132 + ch*8];
      u16x8 ov;
      #pragma unroll
      for (int e=0;e<8;e++) ov[e] = f2b(b2f(xv[e]) + lf[e]);
      *(u16x8*)&xrow[ch*8] = ov;
    }
  } else {
    #pragma unroll
    for (int mt=0;mt<MT;mt++){
      #pragma unroll
      for (int nt=0;nt<4;nt++){
        #pragma unroll
        for (int i=0;i<4;i++){
          int gm = m0 + wm*(BM/2) + mt*16 + gr*4 + i;
          int gn = n0 + wn*64 + nt*16 + cl;
          float val = acc[mt][nt][i];
          if (bias) val += bias[gn];
          outf[(size_t)gm*N + gn] = val;
        }
      }
    }
  }
}

// ---------------- attention: R11-frozen body; heavy tiles dispatched first ----------------
__global__ __launch_bounds__(256,2) void attn_kernel(
    const u16* __restrict__ q, const u16* __restrict__ k, const u16* __restrict__ vt,
    float* __restrict__ att, u16* __restrict__ y, int layer)
{
  __shared__ u16 pl[4][16*64];
  const int lane = threadIdx.x & 63;
  const int w = threadIdx.x >> 6;
  const int qt = 15 - blockIdx.x;
  const int bh = blockIdx.y;
  const int bb = bh / NH_;
  const int hh = bh - bb*NH_;
  const int q0 = qt*64 + w*16;
  const u16* qbase = q + (size_t)bh*T_*HD_;
  const u16* kbase = k + (size_t)bh*T_*HD_;
  const u16* vbase = vt + (size_t)bh*HD_*T_;
  float* abase = att + ((size_t)layer*B_*NH_ + bh)*((size_t)T_*T_);
  u16* plw = &pl[w][0];

  const int cl = lane & 15, gr = lane >> 4;
  const int d0 = gr*8;
  const int swz = (cl & 7)*8;
  const int myq = q0 + cl;

  s16x8 qf0 = *(const s16x8*)(qbase + (size_t)(q0+cl)*HD_ + d0);
  s16x8 qf1 = *(const s16x8*)(qbase + (size_t)(q0+cl)*HD_ + 32 + d0);

  const float scale = 0.125f;
  const int nkt = qt + 1;

  unsigned pbuf[16][8];
  float slocal = 0.f;
  f32x4 yacc[4];
  #pragma unroll
  for (int n=0;n<4;n++) yacc[n] = (f32x4){0.f,0.f,0.f,0.f};

  #pragma unroll
  for (int kt=0; kt<16; kt++){
    if (kt < nkt){
      #pragma unroll
      for (int n=0;n<4;n++){
        int krow = kt*64 + n*16 + cl;
        s16x8 kf0 = *(const s16x8*)(kbase + (size_t)krow*HD_ + d0);
        s16x8 kf1 = *(const s16x8*)(kbase + (size_t)krow*HD_ + 32 + d0);
        f32x4 dacc = (f32x4){0.f,0.f,0.f,0.f};
        dacc = mfma16(kf0, qf0, dacc);
        dacc = mfma16(kf1, qf1, dacc);
        float p[4];
        #pragma unroll
        for (int i=0;i<4;i++){
          float sv = dacc[i]*scale;
          int kk = kt*64 + n*16 + gr*4 + i;
          if (kt == qt && kk > myq) sv = -1e30f;
          p[i] = __expf(sv);
        }
        slocal += (p[0]+p[1]) + (p[2]+p[3]);
        unsigned lo = cvtpk(p[0],p[1]), hi = cvtpk(p[2],p[3]);
        pbuf[kt][2*n]   = lo;
        pbuf[kt][2*n+1] = hi;
        int colb = (n*16 + gr*4) ^ swz;
        *(uint2*)&plw[cl*64 + colb] = make_uint2(lo, hi);
      }
      asm volatile("s_waitcnt lgkmcnt(0)" ::: "memory");
      __builtin_amdgcn_sched_barrier(0);
      #pragma unroll
      for (int cc=0;cc<2;cc++){
        s16x8 pa = *(const s16x8*)&plw[cl*64 + ((cc*32 + d0) ^ swz)];
        #pragma unroll
        for (int n2=0;n2<4;n2++){
          s16x8 bv = *(const s16x8*)(vbase + (size_t)(n2*16+cl)*T_ + kt*64 + cc*32 + d0);
          yacc[n2] = mfma16(pa, bv, yacc[n2]);
        }
      }
    }
  }

  slocal += __shfl_xor(slocal, 16, 64);
  slocal += __shfl_xor(slocal, 32, 64);
  float inv = 1.0f / slocal;

  float invy[4];
  #pragma unroll
  for (int i=0;i<4;i++) invy[i] = __shfl(inv, gr*4 + i, 64);

  #pragma unroll
  for (int n2=0;n2<4;n2++){
    #pragma unroll
    for (int i=0;i<4;i++){
      int r = q0 + gr*4 + i;
      y[((size_t)bb*T_ + r)*C_ + hh*HD_ + n2*16 + cl] = f2b(yacc[n2][i]*invy[i]);
    }
  }

  #pragma unroll
  for (int kt=0; kt<16; kt++){
    if (kt < nkt){
      #pragma unroll
      for (int n=0;n<4;n++){
        unsigned lo = pbuf[kt][2*n], hi = pbuf[kt][2*n+1];
        float p0 = __uint_as_float(lo << 16)          * inv;
        float p1 = __uint_as_float(lo & 0xffff0000u)  * inv;
        float p2 = __uint_as_float(hi << 16)          * inv;
        float p3 = __uint_as_float(hi & 0xffff0000u)  * inv;
        *(float4*)&abase[(size_t)myq*T_ + kt*64 + n*16 + gr*4] = make_float4(p0,p1,p2,p3);
      }
    }
  }

  int kend = nkt*64;
  if (kend < T_){
    int w4 = (T_ - kend) >> 2;
    for (int r = w; r < 64; r += 4){
      float* rp = abase + (size_t)(qt*64 + r)*T_ + kend;
      for (int c = lane; c < w4; c += 64){
        *(float4*)(rp + c*4) = make_float4(0.f,0.f,0.f,0.f);
      }
    }
  }
}

// ---------------- host ----------------
extern "C" void kernel_launch(void* const* d_in, const int* in_sizes, int n_in,
                              void* d_out, int out_size, void* d_ws, size_t ws_size,
                              hipStream_t stream)
{
  (void)in_sizes; (void)n_in; (void)out_size; (void)ws_size;
  const int*   idx  = (const int*)d_in[0];
  const float* tok  = (const float*)d_in[1];
  const float* typ  = (const float*)d_in[2];
  const float* pos  = (const float*)d_in[3];
  const float* ln1s = (const float*)d_in[4];
  const float* ln1b = (const float*)d_in[5];
  const float* ln2s = (const float*)d_in[6];
  const float* ln2b = (const float*)d_in[7];
  const float* wq   = (const float*)d_in[8];
  const float* bq   = (const float*)d_in[9];
  const float* wk   = (const float*)d_in[10];
  const float* bk   = (const float*)d_in[11];
  const float* wv   = (const float*)d_in[12];
  const float* bv   = (const float*)d_in[13];
  const float* wp   = (const float*)d_in[14];
  const float* bp   = (const float*)d_in[15];
  const float* w1   = (const float*)d_in[16];
  const float* b1   = (const float*)d_in[17];
  const float* w2   = (const float*)d_in[18];
  const float* b2   = (const float*)d_in[19];
  const float* lnfs = (const float*)d_in[20];
  const float* lnfb = (const float*)d_in[21];
  const float* hw   = (const float*)d_in[22];

  char* ws = (char*)d_ws;
  u16* x      = (u16*)(ws + 0);
  u16* hbf    = (u16*)(ws + 12582912);
  u16* qb     = (u16*)(ws + 18874368);
  u16* kb     = (u16*)(ws + 25165824);
  u16* vtb    = (u16*)(ws + 31457280);
  u16* yb     = (u16*)(ws + 37748736);
  u16* h2     = (u16*)(ws + 44040192);
  u16* wqkvT  = (u16*)(ws + 69206016);
  u16* wpT    = (u16*)(ws + 83361792);
  u16* w1T    = (u16*)(ws + 88080384);
  u16* w2T    = (u16*)(ws + 106954752);
  u16* hwT    = (u16*)(ws + 125829120);

  float* logits = (float*)d_out;
  float* att = logits + (size_t)B_*T_*V_;

  const size_t CC   = (size_t)C_*C_;
  const size_t CC4  = (size_t)C_*C4_;
  const size_t QKVL = (size_t)3*C_*C_;

  ConvTable tab;
  const float* srcs[7] = {wq, wk, wv, wp, w1, w2, hw};
  u16* dsts[7] = {wqkvT, wqkvT + CC, wqkvT + 2*CC, wpT, w1T, w2T, hwT};
  int Ks[7]   = {C_, C_, C_, C_, C_,  C4_, C_};
  int Ns[7]   = {C_, C_, C_, C_, C4_, C_,  V_};
  int nzs[7]  = {L_, L_, L_, L_, L_,  L_,  1};
  unsigned long long oss[7] = {QKVL, QKVL, QKVL, CC, CC4, CC4, CC};
  int acc = 0;
  for (int j=0;j<7;j++){
    tab.src[j]=srcs[j]; tab.dst[j]=dsts[j]; tab.K[j]=Ks[j]; tab.N[j]=Ns[j];
    tab.nTN[j]=Ns[j]/64; tab.perZ[j]=(Ks[j]/64)*(Ns[j]/64); tab.outStride[j]=oss[j];
    tab.start[j]=acc; acc += tab.perZ[j]*nzs[j];
  }
  tab.start[7]=acc;
  convT_all<<<acc, 256, 0, stream>>>(tab);

  embed_ln_kernel<<<1024, 256, 0, stream>>>(idx, tok, pos, typ + C_, ln1s, ln1b, x, hbf);

  for (int l=0; l<L_; l++){
    if (l > 0)
      ln_kernel<<<1024, 256, 0, stream>>>(x, ln1s + l*C_, ln1b + l*C_, hbf);
    gemm_kernel<64,5,false><<<dim3(18,64), 256, 0, stream>>>(
        hbf, wqkvT + l*QKVL, bq + l*C_, bk + l*C_, bv + l*C_,
        qb, kb, vtb, nullptr, nullptr, 3*C_, C_);
    attn_kernel<<<dim3(16,48), 256, 0, stream>>>(qb, kb, vtb, att, yb, l);
    gemm_kernel<64,3,false><<<dim3(6,64), 256, 0, stream>>>(
        yb, wpT + l*CC, bp + l*C_, nullptr, nullptr,
        nullptr, nullptr, nullptr, nullptr, x, C_, C_);
    ln_kernel<<<1024, 256, 0, stream>>>(x, ln2s + l*C_, ln2b + l*C_, hbf);
    gemm_kernel<64,0,true><<<dim3(24,64), 256, 0, stream>>>(
        hbf, w1T + l*CC4, b1 + l*C4_, nullptr, nullptr,
        h2, nullptr, nullptr, nullptr, nullptr, C4_, C_);
    gemm_kernel<64,3,false><<<dim3(6,64), 256, 0, stream>>>(
        h2, w2T + l*CC4, b2 + l*C_, nullptr, nullptr,
        nullptr, nullptr, nullptr, nullptr, x, C_, C4_);
  }
  ln_kernel<<<1024, 256, 0, stream>>>(x, lnfs, lnfb, hbf);
  gemm_kernel<64,4,false><<<dim3(4,64), 256, 0, stream>>>(
      hbf, hwT, nullptr, nullptr, nullptr,
      nullptr, nullptr, nullptr, logits, nullptr, V_, C_);
}